// Round 5
// baseline (315.472 us; speedup 1.0000x reference)
//
#include <hip/hip_runtime.h>

// Multi-head attention, B=4 S=2048 D=768 H=8 DH=96. FP32 I/O, f16 MFMA compute.
// R13: (a) attn software-pipelined: QK^T(t) issued before softmax+PV(t-1) so
//      VALU/PV hide under MFMA latency (regs sA/sB ping-pong, dbuf K/V).
//      (b) GEMMs: BK=64, XOR chunk-swizzle (col8^=row&7) on gll16 source +
//      matching read XOR -> fragment ds_read_b128 8-way -> 2-way conflicts.
//      (c) gemm_qkv z=2 (V^T) epilogue transposed through LDS -> coalesced
//      128B-contiguous stores (was 8B @ 4KB stride).
// Buffers: ws = [WqT|WkT|WvT|WoT (4.7MB) | Q16 | Xk16 | Xv16 | Xq16] = 55.05MB
//          d_out = [VT (12.6MB) | K16 (12.6MB)] f16 until GEMM_O overwrites.
//          A16 -> Xq buffer (dead after QKV GEMM; harness restores d_in).

typedef unsigned short u16;
typedef _Float16 h16;
typedef h16 h16x8 __attribute__((ext_vector_type(8)));
typedef __fp16 fp16x2 __attribute__((ext_vector_type(2)));
typedef __fp16 fp16x4 __attribute__((ext_vector_type(4)));
typedef unsigned short u16x8 __attribute__((ext_vector_type(8)));
typedef unsigned short u16x4 __attribute__((ext_vector_type(4)));
typedef float f32x4 __attribute__((ext_vector_type(4)));

__device__ __forceinline__ u16 f2h(float f) {
  union { h16 h; u16 u; } c; c.h = (h16)f; return c.u;
}

__device__ __forceinline__ void gll16(const void* g, void* l) {
  __builtin_amdgcn_global_load_lds(
      (const __attribute__((address_space(1))) void*)g,
      (__attribute__((address_space(3))) void*)l, 16, 0, 0);
}

// ---------------------------------------------------------------------------
// prep: LDS-tiled weight transposes + X f16 conversions (unchanged from R12).
// ---------------------------------------------------------------------------
__global__ __launch_bounds__(256) void prep_kernel(
    const float* __restrict__ Wq, const float* __restrict__ Wk,
    const float* __restrict__ Wv, const float* __restrict__ Wo,
    const float* __restrict__ Xk, const float* __restrict__ Xv,
    const float* __restrict__ Xq,
    u16* __restrict__ WqT, u16* __restrict__ WkT,
    u16* __restrict__ WvT, u16* __restrict__ WoT,
    u16* __restrict__ Xk16, u16* __restrict__ Xv16, u16* __restrict__ Xq16)
{
  const int bid = blockIdx.x;
  const int tid = threadIdx.x;

  if (bid >= 432) {
    const int i = bid - 432;
    const int t = i / 3072;                       // 0: Xk  1: Xv  2: Xq
    const long e = ((long)(i % 3072) * 256 + tid) * 8;
    const float* src = (t == 0) ? Xk : (t == 1) ? Xv : Xq;
    u16* dst = (t == 0) ? Xk16 : (t == 1) ? Xv16 : Xq16;
    f32x4 a = *(const f32x4*)(&src[e]);
    f32x4 b = *(const f32x4*)(&src[e + 4]);
    u16x8 v;
    #pragma unroll
    for (int j = 0; j < 4; j++) { v[j] = f2h(a[j]); v[4 + j] = f2h(b[j]); }
    *(u16x8*)(&dst[e]) = v;
    return;
  }

  if (bid < 288) {
    __shared__ u16 Lt[96][72];
    const int w = bid / 96;
    const int r = bid % 96;
    const int h = r / 12, dt = r % 12;
    const float* W = (w == 0) ? Wq : (w == 1) ? Wk : Wv;
    u16* T = (w == 0) ? WqT : (w == 1) ? WkT : WvT;
    const float* src = W + (size_t)h * 73728 + (size_t)dt * 64 * 96;
    #pragma unroll
    for (int p = 0; p < 6; p++) {
      const int lin = p * 1024 + tid * 4;
      f32x4 v = *(const f32x4*)(&src[lin]);
      const int d = lin / 96, kk = lin % 96;
      #pragma unroll
      for (int j = 0; j < 4; j++) Lt[kk + j][d] = f2h(v[j]);
    }
    __syncthreads();
    #pragma unroll
    for (int c = 0; c < 3; c++) {
      const int ch = c * 256 + tid;
      const int kk = ch >> 3, dc = ch & 7;
      u16x8 o = *(const u16x8*)(&Lt[kk][dc * 8]);
      *(u16x8*)(&T[(size_t)(h * 96 + kk) * 768 + dt * 64 + dc * 8]) = o;
    }
    return;
  }

  {
    __shared__ u16 Lo[64][72];
    const int i = bid - 288;
    const int kt = i / 12, nt = i % 12;
    const float* src = Wo + (size_t)(kt * 64) * 768 + nt * 64;
    #pragma unroll
    for (int p = 0; p < 4; p++) {
      const int lin = p * 1024 + tid * 4;
      const int kr = lin >> 6, nc = lin & 63;
      f32x4 v = *(const f32x4*)(&src[(size_t)kr * 768 + nc]);
      #pragma unroll
      for (int j = 0; j < 4; j++) Lo[nc + j][kr] = f2h(v[j]);
    }
    __syncthreads();
    #pragma unroll
    for (int c = 0; c < 2; c++) {
      const int ch = c * 256 + tid;
      const int nr = ch >> 3, kc = ch & 7;
      u16x8 o = *(const u16x8*)(&Lo[nr][kc * 8]);
      *(u16x8*)(&WoT[(size_t)(nt * 64 + nr) * 768 + kt * 64 + kc * 8]) = o;
    }
  }
}

// ---------------------------------------------------------------------------
// Batched QKV GEMM, BM=128 BN=128 BK=64, gll16 staging with XOR chunk-swizzle
// (pre-swizzled global source, XOR'd fragment reads -> 2-way conflicts).
// z=2 writes V^T via LDS transpose (coalesced). grid (64, 6, 3), 256 thr.
// ---------------------------------------------------------------------------
#define GK 768

__global__ __launch_bounds__(256) void gemm_qkv(
    const u16* __restrict__ Xq16, const u16* __restrict__ Xk16,
    const u16* __restrict__ Xv16, const u16* __restrict__ WT,
    const float* __restrict__ bq, const float* __restrict__ bk,
    const float* __restrict__ bv,
    u16* __restrict__ Q16, u16* __restrict__ K16, u16* __restrict__ VT)
{
  const int z = blockIdx.z;
  const u16* BT = WT + (size_t)z * 589824;
  const float* bias = (z == 0) ? bq : (z == 1) ? bk : bv;
  const u16* A = (z == 0) ? Xq16 : (z == 1) ? Xk16 : Xv16;

  __shared__ __align__(16) u16 S[16384];     // As[128*64] | Bs[128*64] (32KB)
  u16* As = S;
  u16* Bs = S + 8192;

  const int tid = threadIdx.x;
  const int wave = tid >> 6;
  const int lane = tid & 63;
  const int quad = lane >> 4;
  const int l16 = lane & 15;
  const int m0 = blockIdx.x * 128;
  const int n0 = blockIdx.y * 128;

  f32x4 acc[2][8];
  #pragma unroll
  for (int i = 0; i < 2; i++)
    #pragma unroll
    for (int j = 0; j < 8; j++) acc[i][j] = (f32x4){0.f, 0.f, 0.f, 0.f};

  // staging geometry: chunk c = p*256+tid -> row=c>>3, col8=c&7, src col
  // pre-swizzled (col8 ^ row&7) so linear LDS + XOR'd reads line up (T2/m173).
  int srow[4], scol[4];
  #pragma unroll
  for (int p = 0; p < 4; p++) {
    const int c = p * 256 + tid;
    srow[p] = c >> 3;
    scol[p] = ((c & 7) ^ (srow[p] & 7)) << 3;
  }
  const int x7 = (l16 & 7) << 3;

  for (int kt = 0; kt < 12; kt++) {
    const int k0 = kt * 64;
    #pragma unroll
    for (int p = 0; p < 4; p++) {
      gll16(&A[(size_t)(m0 + srow[p]) * GK + k0 + scol[p]],
            As + (size_t)(p * 256 + wave * 64) * 8);
      gll16(&BT[(size_t)(n0 + srow[p]) * GK + k0 + scol[p]],
            Bs + (size_t)(p * 256 + wave * 64) * 8);
    }
    __syncthreads();

    #pragma unroll
    for (int ks2 = 0; ks2 < 2; ks2++) {
      const int cc = (ks2 * 32 + quad * 8) ^ x7;
      h16x8 af[2], bf[8];
      #pragma unroll
      for (int mf = 0; mf < 2; mf++)
        af[mf] = *(const h16x8*)(&As[(wave * 32 + mf * 16 + l16) * 64 + cc]);
      #pragma unroll
      for (int nf = 0; nf < 8; nf++)
        bf[nf] = *(const h16x8*)(&Bs[(nf * 16 + l16) * 64 + cc]);
      #pragma unroll
      for (int mf = 0; mf < 2; mf++)
        #pragma unroll
        for (int nf = 0; nf < 8; nf++)
          acc[mf][nf] = __builtin_amdgcn_mfma_f32_16x16x32_f16(af[mf], bf[nf], acc[mf][nf], 0, 0, 0);
    }
    __syncthreads();
  }

  if (z == 2) {
    // V^T via LDS transpose: Ts[64 n][136] halves, coalesced u16x8 stores.
    const int b = m0 >> 11, s0 = m0 & 2047;
    u16* Ts = S;
    #pragma unroll
    for (int half = 0; half < 2; half++) {
      __syncthreads();
      #pragma unroll
      for (int nf2 = 0; nf2 < 4; nf2++) {
        const int nf = half * 4 + nf2;
        const float bv2 = bias[n0 + nf * 16 + l16];
        #pragma unroll
        for (int mf = 0; mf < 2; mf++)
          #pragma unroll
          for (int r = 0; r < 4; r++)
            Ts[(nf2 * 16 + l16) * 136 + wave * 32 + mf * 16 + quad * 4 + r] =
                f2h(acc[mf][nf][r] + bv2);
      }
      __syncthreads();
      #pragma unroll
      for (int p = 0; p < 4; p++) {
        const int c = p * 256 + tid;
        const int row = c >> 4, col8 = (c & 15) * 8;
        u16x8 o8 = *(const u16x8*)(&Ts[row * 136 + col8]);
        *(u16x8*)(&VT[(size_t)b * 768 * 2048 +
                      (size_t)(n0 + half * 64 + row) * 2048 + s0 + col8]) = o8;
      }
    }
    return;
  }

  u16* Yr = (z == 0) ? Q16 : K16;
  #pragma unroll
  for (int nf = 0; nf < 8; nf++) {
    const int n = n0 + nf * 16 + l16;
    const float bv2 = bias[n];
    #pragma unroll
    for (int mf = 0; mf < 2; mf++) {
      const int m = m0 + wave * 32 + mf * 16 + quad * 4;
      #pragma unroll
      for (int r = 0; r < 4; r++)
        Yr[(size_t)(m + r) * GK + n] = f2h(acc[mf][nf][r] + bv2);
    }
  }
}

// ---------------------------------------------------------------------------
// GEMM_O: out[8192][768] fp32 = A16 f16 @ WoT + bo. BK=64 + swizzle. grid (64,6).
// ---------------------------------------------------------------------------
__global__ __launch_bounds__(256) void gemm_o(
    const u16* __restrict__ A, const u16* __restrict__ BT,
    const float* __restrict__ bias, float* __restrict__ Y)
{
  __shared__ __align__(16) u16 S[16384];
  u16* As = S;
  u16* Bs = S + 8192;

  const int tid = threadIdx.x;
  const int wave = tid >> 6;
  const int lane = tid & 63;
  const int quad = lane >> 4;
  const int l16 = lane & 15;
  const int m0 = blockIdx.x * 128;
  const int n0 = blockIdx.y * 128;

  f32x4 acc[2][8];
  #pragma unroll
  for (int i = 0; i < 2; i++)
    #pragma unroll
    for (int j = 0; j < 8; j++) acc[i][j] = (f32x4){0.f, 0.f, 0.f, 0.f};

  int srow[4], scol[4];
  #pragma unroll
  for (int p = 0; p < 4; p++) {
    const int c = p * 256 + tid;
    srow[p] = c >> 3;
    scol[p] = ((c & 7) ^ (srow[p] & 7)) << 3;
  }
  const int x7 = (l16 & 7) << 3;

  for (int kt = 0; kt < 12; kt++) {
    const int k0 = kt * 64;
    #pragma unroll
    for (int p = 0; p < 4; p++) {
      gll16(&A[(size_t)(m0 + srow[p]) * GK + k0 + scol[p]],
            As + (size_t)(p * 256 + wave * 64) * 8);
      gll16(&BT[(size_t)(n0 + srow[p]) * GK + k0 + scol[p]],
            Bs + (size_t)(p * 256 + wave * 64) * 8);
    }
    __syncthreads();

    #pragma unroll
    for (int ks2 = 0; ks2 < 2; ks2++) {
      const int cc = (ks2 * 32 + quad * 8) ^ x7;
      h16x8 af[2], bf[8];
      #pragma unroll
      for (int mf = 0; mf < 2; mf++)
        af[mf] = *(const h16x8*)(&As[(wave * 32 + mf * 16 + l16) * 64 + cc]);
      #pragma unroll
      for (int nf = 0; nf < 8; nf++)
        bf[nf] = *(const h16x8*)(&Bs[(nf * 16 + l16) * 64 + cc]);
      #pragma unroll
      for (int mf = 0; mf < 2; mf++)
        #pragma unroll
        for (int nf = 0; nf < 8; nf++)
          acc[mf][nf] = __builtin_amdgcn_mfma_f32_16x16x32_f16(af[mf], bf[nf], acc[mf][nf], 0, 0, 0);
    }
    __syncthreads();
  }

  #pragma unroll
  for (int nf = 0; nf < 8; nf++) {
    const int n = n0 + nf * 16 + l16;
    const float bv = bias[n];
    #pragma unroll
    for (int mf = 0; mf < 2; mf++) {
      const int m = m0 + wave * 32 + mf * 16 + quad * 4;
      #pragma unroll
      for (int r = 0; r < 4; r++)
        Y[(size_t)(m + r) * GK + n] = acc[mf][nf][r] + bv;
    }
  }
}

// ---------------------------------------------------------------------------
// Flash attention, software-pipelined: per phase, QK^T(t) MFMAs issue first,
// then softmax+PV(t-1) (register-independent -> VALU hides under MFMA).
// 512 thr / 8 waves x 16 q-rows, grid (16,32), dbuf K/V (72.7KB, 2 blk/CU).
// defer-max (T13); setprio (T5).
// ---------------------------------------------------------------------------
#define SEQ 2048
#define NT 32
#define LQK 104
#define LVT 72
#define LPS 72

__global__ __launch_bounds__(512, 4) void attn_kernel(
    const u16* __restrict__ Q, const u16* __restrict__ K,
    const u16* __restrict__ VT, u16* __restrict__ O)
{
  __shared__ __align__(16) u16 Ks[2][64 * LQK];
  __shared__ __align__(16) u16 Vt[2][96 * LVT];
  __shared__ __align__(16) u16 Ps[8][16 * LPS];

  const int tid = threadIdx.x;
  const int wave = tid >> 6;
  const int lane = tid & 63;
  const int quad = lane >> 4;
  const int l16 = lane & 15;

  const int bh = blockIdx.y;
  const int b = bh >> 3, h = bh & 7;
  const int q0 = blockIdx.x * 128;

  const size_t batch_off = (size_t)b * SEQ * 768;
  const u16* Kg = K + batch_off + h * 96;
  const u16* Vg = VT + (size_t)b * 768 * 2048 + (size_t)(h * 96) * 2048;

  h16x8 qf[3];
  {
    const u16* Qrow = Q + batch_off + (size_t)(q0 + wave * 16 + l16) * 768 + h * 96 + quad * 8;
    #pragma unroll
    for (int ks = 0; ks < 3; ks++) qf[ks] = *(const h16x8*)(&Qrow[ks * 32]);
  }

  const int kr0 = tid / 12, kc0 = (tid % 12) * 8;
  const int kr1 = (tid + 512) / 12, kc1 = ((tid + 512) % 12) * 8;
  const int vr0 = tid >> 3, vc0 = (tid & 7) * 8;
  const int vr1 = (tid + 512) >> 3, vc1 = ((tid + 512) & 7) * 8;
  const bool extra = tid < 256;

  f32x4 o[6];
  #pragma unroll
  for (int i = 0; i < 6; i++) o[i] = (f32x4){0.f, 0.f, 0.f, 0.f};
  float m_raw = -1e30f, lrow = 0.f;
  const float sc = 0.14724498f;       // log2(e)/sqrt(96)

  u16* Pw = &Ps[wave][0];

  u16x8 kA, kB, vA, vB;

  auto load_tile = [&](int t) {
    const u16* Kn = Kg + (size_t)t * 64 * 768;
    const u16* Vn = Vg + (size_t)t * 64;
    kA = *(const u16x8*)(&Kn[(size_t)kr0 * 768 + kc0]);
    vA = *(const u16x8*)(&Vn[(size_t)vr0 * 2048 + vc0]);
    if (extra) {
      kB = *(const u16x8*)(&Kn[(size_t)kr1 * 768 + kc1]);
      vB = *(const u16x8*)(&Vn[(size_t)vr1 * 2048 + vc1]);
    }
  };
  auto stage_write = [&](int buf) {
    *(u16x8*)(&Ks[buf][kr0 * LQK + kc0]) = kA;
    *(u16x8*)(&Vt[buf][vr0 * LVT + vc0]) = vA;
    if (extra) {
      *(u16x8*)(&Ks[buf][kr1 * LQK + kc1]) = kB;
      *(u16x8*)(&Vt[buf][vr1 * LVT + vc1]) = vB;
    }
  };
  auto qkt = [&](f32x4 (&s)[4], const u16* Kc) {
    #pragma unroll
    for (int kf = 0; kf < 4; kf++) s[kf] = (f32x4){0.f, 0.f, 0.f, 0.f};
    __builtin_amdgcn_s_setprio(1);
    #pragma unroll
    for (int ks = 0; ks < 3; ks++) {
      #pragma unroll
      for (int kf = 0; kf < 4; kf++) {
        h16x8 a = *(const h16x8*)(&Kc[(kf * 16 + l16) * LQK + ks * 32 + quad * 8]);
        s[kf] = __builtin_amdgcn_mfma_f32_16x16x32_f16(a, qf[ks], s[kf], 0, 0, 0);
      }
    }
    __builtin_amdgcn_s_setprio(0);
  };
  auto process = [&](f32x4 (&s)[4], const u16* Vc) {
    float mx = s[0][0];
    #pragma unroll
    for (int kf = 0; kf < 4; kf++)
      #pragma unroll
      for (int r = 0; r < 4; r++) mx = fmaxf(mx, s[kf][r]);
    mx = fmaxf(mx, __shfl_xor(mx, 16));
    mx = fmaxf(mx, __shfl_xor(mx, 32));
    if (__any(mx > m_raw + 54.0f)) {
      const float mnew = fmaxf(m_raw, mx);
      const float alpha = exp2f(sc * (m_raw - mnew));   // 0 on first tile
      lrow *= alpha;
      #pragma unroll
      for (int nfo = 0; nfo < 6; nfo++)
        #pragma unroll
        for (int r = 0; r < 4; r++) o[nfo][r] *= alpha;
      m_raw = mnew;
    }
    const float c0 = sc * m_raw;
    float ps = 0.f;
    #pragma unroll
    for (int kf = 0; kf < 4; kf++)
      #pragma unroll
      for (int r = 0; r < 4; r++) {
        float p = exp2f(fmaf(s[kf][r], sc, -c0));
        s[kf][r] = p;
        ps += p;
      }
    lrow += ps;
    #pragma unroll
    for (int kf = 0; kf < 4; kf++) {
      fp16x2 a2 = __builtin_amdgcn_cvt_pkrtz(s[kf][0], s[kf][1]);
      fp16x2 b2 = __builtin_amdgcn_cvt_pkrtz(s[kf][2], s[kf][3]);
      fp16x4 w4; w4[0] = a2[0]; w4[1] = a2[1]; w4[2] = b2[0]; w4[3] = b2[1];
      *(fp16x4*)(&Pw[l16 * LPS + kf * 16 + quad * 4]) = w4;
    }
    __builtin_amdgcn_s_setprio(1);
    #pragma unroll
    for (int ks = 0; ks < 2; ks++) {
      h16x8 pfr = *(const h16x8*)(&Pw[l16 * LPS + ks * 32 + quad * 8]);
      #pragma unroll
      for (int nfo = 0; nfo < 6; nfo++) {
        h16x8 vfr = *(const h16x8*)(&Vc[(nfo * 16 + l16) * LVT + ks * 32 + quad * 8]);
        o[nfo] = __builtin_amdgcn_mfma_f32_16x16x32_f16(vfr, pfr, o[nfo], 0, 0, 0);
      }
    }
    __builtin_amdgcn_s_setprio(0);
  };

  // prolog: stage tiles 0,1; preload tile 2; compute scores(0)
  load_tile(0); stage_write(0);
  load_tile(1); stage_write(1);
  load_tile(2);
  __syncthreads();

  f32x4 sA[4], sB[4];
  qkt(sA, &Ks[0][0]);

  for (int t = 1; t < NT - 1; t += 2) {
    // phase A: tile t (odd, buf1); finish tile t-1 (buf0)
    qkt(sB, &Ks[1][0]);
    process(sA, &Vt[0][0]);
    __syncthreads();
    stage_write(0);                       // tile t+1 -> buf0
    if (t + 2 < NT) load_tile(t + 2);
    __syncthreads();
    // phase B: tile t+1 (even, buf0); finish tile t (buf1)
    qkt(sA, &Ks[0][0]);
    process(sB, &Vt[1][0]);
    __syncthreads();
    stage_write(1);                       // tile t+2 -> buf1
    if (t + 3 < NT) load_tile(t + 3);
    __syncthreads();
  }
  // tail: tile 31 in buf1; finish tiles 30 (sA, buf0) and 31 (sB, buf1)
  qkt(sB, &Ks[1][0]);
  process(sA, &Vt[0][0]);
  process(sB, &Vt[1][0]);

  lrow += __shfl_xor(lrow, 16);
  lrow += __shfl_xor(lrow, 32);
  const float inv = 1.0f / lrow;
  u16* Ob = O + batch_off + (size_t)(q0 + wave * 16 + l16) * 768 + h * 96;
  #pragma unroll
  for (int nfo = 0; nfo < 6; nfo++) {
    fp16x2 lo = __builtin_amdgcn_cvt_pkrtz(o[nfo][0] * inv, o[nfo][1] * inv);
    fp16x2 hi = __builtin_amdgcn_cvt_pkrtz(o[nfo][2] * inv, o[nfo][3] * inv);
    *(fp16x2*)(&Ob[nfo * 16 + quad * 4]) = lo;
    *(fp16x2*)(&Ob[nfo * 16 + quad * 4 + 2]) = hi;
  }
}

// ---------------------------------------------------------------------------
extern "C" void kernel_launch(void* const* d_in, const int* in_sizes, int n_in,
                              void* d_out, int out_size, void* d_ws, size_t ws_size,
                              hipStream_t stream) {
  const float* Xq = (const float*)d_in[0];
  const float* Xk = (const float*)d_in[1];
  const float* Xv = (const float*)d_in[2];
  const float* Wq = (const float*)d_in[3];
  const float* bq = (const float*)d_in[4];
  const float* Wk = (const float*)d_in[5];
  const float* bk = (const float*)d_in[6];
  const float* Wv = (const float*)d_in[7];
  const float* bv = (const float*)d_in[8];
  const float* Wo = (const float*)d_in[9];
  const float* bo = (const float*)d_in[10];

  u16* wsu = (u16*)d_ws;
  u16* WT   = wsu;                    // WqT | WkT | WvT, 589824 each
  u16* WoT  = wsu + 3 * 589824;
  u16* Q16  = wsu + 4 * 589824;       // 12.6 MB
  u16* Xk16 = Q16 + 6291456;          // 12.6 MB
  u16* Xv16 = Xk16 + 6291456;         // 12.6 MB
  u16* Xq16 = Xv16 + 6291456;         // 12.6 MB (total 55.05 MB)

  u16* outu = (u16*)d_out;
  u16* VTb = outu;                   // V^T f16 [4][768][2048]
  u16* K16 = outu + 6291456;         // K f16 rowmajor

  u16* A16 = (u16*)d_in[0];          // attn out (Xq dead after QKV GEMM)

  prep_kernel<<<9648, 256, 0, stream>>>(
      Wq, Wk, Wv, Wo, Xk, Xv, Xq,
      WT, WT + 589824, WT + 2 * 589824, WoT, Xk16, Xv16, Xq16);
  gemm_qkv<<<dim3(64, 6, 3), 256, 0, stream>>>(
      Xq16, Xk16, Xv16, WT, bq, bk, bv, Q16, K16, VTb);
  attn_kernel<<<dim3(16, 32), 512, 0, stream>>>(Q16, K16, VTb, A16);
  gemm_o<<<dim3(64, 6), 256, 0, stream>>>(A16, WoT, bo, (float*)d_out);
}

// Round 6
// 286.733 us; speedup vs baseline: 1.1002x; 1.1002x over previous
//
#include <hip/hip_runtime.h>

// Multi-head attention, B=4 S=2048 D=768 H=8 DH=96. FP32 I/O, f16 MFMA compute.
// R14: (a) attn reverted to R4 structure (dbuf K/V, one barrier/iter,
//      write-late staging) -- known 100.3us.
//      (b) GEMMs kept from R5 (BK=64, XOR chunk swizzle, coalesced VT store).
//      (c) A16 (attn output) moved from d_in[0] overlay to ws overlay on Xk16
//      (dead after gemm_qkv) -- d_in is now never written, eliminating any
//      harness input-restore cost between timed iterations.
// Buffers: ws = [WqT|WkT|WvT|WoT (4.7MB) | Q16 | Xk16 | Xv16 | Xq16] = 55.05MB
//          A16 overlays Xk16 after gemm_qkv.
//          d_out = [VT (12.6MB) | K16 (12.6MB)] f16 until GEMM_O overwrites.

typedef unsigned short u16;
typedef _Float16 h16;
typedef h16 h16x8 __attribute__((ext_vector_type(8)));
typedef __fp16 fp16x2 __attribute__((ext_vector_type(2)));
typedef __fp16 fp16x4 __attribute__((ext_vector_type(4)));
typedef unsigned short u16x8 __attribute__((ext_vector_type(8)));
typedef unsigned short u16x4 __attribute__((ext_vector_type(4)));
typedef float f32x4 __attribute__((ext_vector_type(4)));

__device__ __forceinline__ u16 f2h(float f) {
  union { h16 h; u16 u; } c; c.h = (h16)f; return c.u;
}

__device__ __forceinline__ void gll16(const void* g, void* l) {
  __builtin_amdgcn_global_load_lds(
      (const __attribute__((address_space(1))) void*)g,
      (__attribute__((address_space(3))) void*)l, 16, 0, 0);
}

// ---------------------------------------------------------------------------
// prep: LDS-tiled weight transposes + X f16 conversions.
// ---------------------------------------------------------------------------
__global__ __launch_bounds__(256) void prep_kernel(
    const float* __restrict__ Wq, const float* __restrict__ Wk,
    const float* __restrict__ Wv, const float* __restrict__ Wo,
    const float* __restrict__ Xk, const float* __restrict__ Xv,
    const float* __restrict__ Xq,
    u16* __restrict__ WqT, u16* __restrict__ WkT,
    u16* __restrict__ WvT, u16* __restrict__ WoT,
    u16* __restrict__ Xk16, u16* __restrict__ Xv16, u16* __restrict__ Xq16)
{
  const int bid = blockIdx.x;
  const int tid = threadIdx.x;

  if (bid >= 432) {
    const int i = bid - 432;
    const int t = i / 3072;                       // 0: Xk  1: Xv  2: Xq
    const long e = ((long)(i % 3072) * 256 + tid) * 8;
    const float* src = (t == 0) ? Xk : (t == 1) ? Xv : Xq;
    u16* dst = (t == 0) ? Xk16 : (t == 1) ? Xv16 : Xq16;
    f32x4 a = *(const f32x4*)(&src[e]);
    f32x4 b = *(const f32x4*)(&src[e + 4]);
    u16x8 v;
    #pragma unroll
    for (int j = 0; j < 4; j++) { v[j] = f2h(a[j]); v[4 + j] = f2h(b[j]); }
    *(u16x8*)(&dst[e]) = v;
    return;
  }

  if (bid < 288) {
    __shared__ u16 Lt[96][72];
    const int w = bid / 96;
    const int r = bid % 96;
    const int h = r / 12, dt = r % 12;
    const float* W = (w == 0) ? Wq : (w == 1) ? Wk : Wv;
    u16* T = (w == 0) ? WqT : (w == 1) ? WkT : WvT;
    const float* src = W + (size_t)h * 73728 + (size_t)dt * 64 * 96;
    #pragma unroll
    for (int p = 0; p < 6; p++) {
      const int lin = p * 1024 + tid * 4;
      f32x4 v = *(const f32x4*)(&src[lin]);
      const int d = lin / 96, kk = lin % 96;
      #pragma unroll
      for (int j = 0; j < 4; j++) Lt[kk + j][d] = f2h(v[j]);
    }
    __syncthreads();
    #pragma unroll
    for (int c = 0; c < 3; c++) {
      const int ch = c * 256 + tid;
      const int kk = ch >> 3, dc = ch & 7;
      u16x8 o = *(const u16x8*)(&Lt[kk][dc * 8]);
      *(u16x8*)(&T[(size_t)(h * 96 + kk) * 768 + dt * 64 + dc * 8]) = o;
    }
    return;
  }

  {
    __shared__ u16 Lo[64][72];
    const int i = bid - 288;
    const int kt = i / 12, nt = i % 12;
    const float* src = Wo + (size_t)(kt * 64) * 768 + nt * 64;
    #pragma unroll
    for (int p = 0; p < 4; p++) {
      const int lin = p * 1024 + tid * 4;
      const int kr = lin >> 6, nc = lin & 63;
      f32x4 v = *(const f32x4*)(&src[(size_t)kr * 768 + nc]);
      #pragma unroll
      for (int j = 0; j < 4; j++) Lo[nc + j][kr] = f2h(v[j]);
    }
    __syncthreads();
    #pragma unroll
    for (int c = 0; c < 2; c++) {
      const int ch = c * 256 + tid;
      const int nr = ch >> 3, kc = ch & 7;
      u16x8 o = *(const u16x8*)(&Lo[nr][kc * 8]);
      *(u16x8*)(&WoT[(size_t)(nt * 64 + nr) * 768 + kt * 64 + kc * 8]) = o;
    }
  }
}

// ---------------------------------------------------------------------------
// Batched QKV GEMM, BM=128 BN=128 BK=64, gll16 staging with XOR chunk-swizzle.
// z=2 writes V^T via LDS transpose (coalesced). grid (64, 6, 3), 256 thr.
// ---------------------------------------------------------------------------
#define GK 768

__global__ __launch_bounds__(256) void gemm_qkv(
    const u16* __restrict__ Xq16, const u16* __restrict__ Xk16,
    const u16* __restrict__ Xv16, const u16* __restrict__ WT,
    const float* __restrict__ bq, const float* __restrict__ bk,
    const float* __restrict__ bv,
    u16* __restrict__ Q16, u16* __restrict__ K16, u16* __restrict__ VT)
{
  const int z = blockIdx.z;
  const u16* BT = WT + (size_t)z * 589824;
  const float* bias = (z == 0) ? bq : (z == 1) ? bk : bv;
  const u16* A = (z == 0) ? Xq16 : (z == 1) ? Xk16 : Xv16;

  __shared__ __align__(16) u16 S[16384];     // As[128*64] | Bs[128*64] (32KB)
  u16* As = S;
  u16* Bs = S + 8192;

  const int tid = threadIdx.x;
  const int wave = tid >> 6;
  const int lane = tid & 63;
  const int quad = lane >> 4;
  const int l16 = lane & 15;
  const int m0 = blockIdx.x * 128;
  const int n0 = blockIdx.y * 128;

  f32x4 acc[2][8];
  #pragma unroll
  for (int i = 0; i < 2; i++)
    #pragma unroll
    for (int j = 0; j < 8; j++) acc[i][j] = (f32x4){0.f, 0.f, 0.f, 0.f};

  int srow[4], scol[4];
  #pragma unroll
  for (int p = 0; p < 4; p++) {
    const int c = p * 256 + tid;
    srow[p] = c >> 3;
    scol[p] = ((c & 7) ^ (srow[p] & 7)) << 3;
  }
  const int x7 = (l16 & 7) << 3;

  for (int kt = 0; kt < 12; kt++) {
    const int k0 = kt * 64;
    #pragma unroll
    for (int p = 0; p < 4; p++) {
      gll16(&A[(size_t)(m0 + srow[p]) * GK + k0 + scol[p]],
            As + (size_t)(p * 256 + wave * 64) * 8);
      gll16(&BT[(size_t)(n0 + srow[p]) * GK + k0 + scol[p]],
            Bs + (size_t)(p * 256 + wave * 64) * 8);
    }
    __syncthreads();

    #pragma unroll
    for (int ks2 = 0; ks2 < 2; ks2++) {
      const int cc = (ks2 * 32 + quad * 8) ^ x7;
      h16x8 af[2], bf[8];
      #pragma unroll
      for (int mf = 0; mf < 2; mf++)
        af[mf] = *(const h16x8*)(&As[(wave * 32 + mf * 16 + l16) * 64 + cc]);
      #pragma unroll
      for (int nf = 0; nf < 8; nf++)
        bf[nf] = *(const h16x8*)(&Bs[(nf * 16 + l16) * 64 + cc]);
      #pragma unroll
      for (int mf = 0; mf < 2; mf++)
        #pragma unroll
        for (int nf = 0; nf < 8; nf++)
          acc[mf][nf] = __builtin_amdgcn_mfma_f32_16x16x32_f16(af[mf], bf[nf], acc[mf][nf], 0, 0, 0);
    }
    __syncthreads();
  }

  if (z == 2) {
    const int b = m0 >> 11, s0 = m0 & 2047;
    u16* Ts = S;
    #pragma unroll
    for (int half = 0; half < 2; half++) {
      __syncthreads();
      #pragma unroll
      for (int nf2 = 0; nf2 < 4; nf2++) {
        const int nf = half * 4 + nf2;
        const float bv2 = bias[n0 + nf * 16 + l16];
        #pragma unroll
        for (int mf = 0; mf < 2; mf++)
          #pragma unroll
          for (int r = 0; r < 4; r++)
            Ts[(nf2 * 16 + l16) * 136 + wave * 32 + mf * 16 + quad * 4 + r] =
                f2h(acc[mf][nf][r] + bv2);
      }
      __syncthreads();
      #pragma unroll
      for (int p = 0; p < 4; p++) {
        const int c = p * 256 + tid;
        const int row = c >> 4, col8 = (c & 15) * 8;
        u16x8 o8 = *(const u16x8*)(&Ts[row * 136 + col8]);
        *(u16x8*)(&VT[(size_t)b * 768 * 2048 +
                      (size_t)(n0 + half * 64 + row) * 2048 + s0 + col8]) = o8;
      }
    }
    return;
  }

  u16* Yr = (z == 0) ? Q16 : K16;
  #pragma unroll
  for (int nf = 0; nf < 8; nf++) {
    const int n = n0 + nf * 16 + l16;
    const float bv2 = bias[n];
    #pragma unroll
    for (int mf = 0; mf < 2; mf++) {
      const int m = m0 + wave * 32 + mf * 16 + quad * 4;
      #pragma unroll
      for (int r = 0; r < 4; r++)
        Yr[(size_t)(m + r) * GK + n] = f2h(acc[mf][nf][r] + bv2);
    }
  }
}

// ---------------------------------------------------------------------------
// GEMM_O: out[8192][768] fp32 = A16 f16 @ WoT + bo. BK=64 + swizzle. grid (64,6).
// ---------------------------------------------------------------------------
__global__ __launch_bounds__(256) void gemm_o(
    const u16* __restrict__ A, const u16* __restrict__ BT,
    const float* __restrict__ bias, float* __restrict__ Y)
{
  __shared__ __align__(16) u16 S[16384];
  u16* As = S;
  u16* Bs = S + 8192;

  const int tid = threadIdx.x;
  const int wave = tid >> 6;
  const int lane = tid & 63;
  const int quad = lane >> 4;
  const int l16 = lane & 15;
  const int m0 = blockIdx.x * 128;
  const int n0 = blockIdx.y * 128;

  f32x4 acc[2][8];
  #pragma unroll
  for (int i = 0; i < 2; i++)
    #pragma unroll
    for (int j = 0; j < 8; j++) acc[i][j] = (f32x4){0.f, 0.f, 0.f, 0.f};

  int srow[4], scol[4];
  #pragma unroll
  for (int p = 0; p < 4; p++) {
    const int c = p * 256 + tid;
    srow[p] = c >> 3;
    scol[p] = ((c & 7) ^ (srow[p] & 7)) << 3;
  }
  const int x7 = (l16 & 7) << 3;

  for (int kt = 0; kt < 12; kt++) {
    const int k0 = kt * 64;
    #pragma unroll
    for (int p = 0; p < 4; p++) {
      gll16(&A[(size_t)(m0 + srow[p]) * GK + k0 + scol[p]],
            As + (size_t)(p * 256 + wave * 64) * 8);
      gll16(&BT[(size_t)(n0 + srow[p]) * GK + k0 + scol[p]],
            Bs + (size_t)(p * 256 + wave * 64) * 8);
    }
    __syncthreads();

    #pragma unroll
    for (int ks2 = 0; ks2 < 2; ks2++) {
      const int cc = (ks2 * 32 + quad * 8) ^ x7;
      h16x8 af[2], bf[8];
      #pragma unroll
      for (int mf = 0; mf < 2; mf++)
        af[mf] = *(const h16x8*)(&As[(wave * 32 + mf * 16 + l16) * 64 + cc]);
      #pragma unroll
      for (int nf = 0; nf < 8; nf++)
        bf[nf] = *(const h16x8*)(&Bs[(nf * 16 + l16) * 64 + cc]);
      #pragma unroll
      for (int mf = 0; mf < 2; mf++)
        #pragma unroll
        for (int nf = 0; nf < 8; nf++)
          acc[mf][nf] = __builtin_amdgcn_mfma_f32_16x16x32_f16(af[mf], bf[nf], acc[mf][nf], 0, 0, 0);
    }
    __syncthreads();
  }

  #pragma unroll
  for (int nf = 0; nf < 8; nf++) {
    const int n = n0 + nf * 16 + l16;
    const float bv = bias[n];
    #pragma unroll
    for (int mf = 0; mf < 2; mf++) {
      const int m = m0 + wave * 32 + mf * 16 + quad * 4;
      #pragma unroll
      for (int r = 0; r < 4; r++)
        Y[(size_t)(m + r) * GK + n] = acc[mf][nf][r] + bv;
    }
  }
}

// ---------------------------------------------------------------------------
// Flash attention (R4: dbuf K/V, one barrier/iter, write-late staging).
// 512 thr / 8 waves x 16 q-rows, grid (16,32). LDS 72.7KB -> 2 blocks/CU.
// defer-max (T13); setprio (T5).
// ---------------------------------------------------------------------------
#define SEQ 2048
#define NT 32
#define LQK 104
#define LVT 72
#define LPS 72

__global__ __launch_bounds__(512, 4) void attn_kernel(
    const u16* __restrict__ Q, const u16* __restrict__ K,
    const u16* __restrict__ VT, u16* __restrict__ O)
{
  __shared__ __align__(16) u16 Ks[2][64 * LQK];
  __shared__ __align__(16) u16 Vt[2][96 * LVT];
  __shared__ __align__(16) u16 Ps[8][16 * LPS];

  const int tid = threadIdx.x;
  const int wave = tid >> 6;
  const int lane = tid & 63;
  const int quad = lane >> 4;
  const int l16 = lane & 15;

  const int bh = blockIdx.y;
  const int b = bh >> 3, h = bh & 7;
  const int q0 = blockIdx.x * 128;

  const size_t batch_off = (size_t)b * SEQ * 768;
  const u16* Kg = K + batch_off + h * 96;
  const u16* Vg = VT + (size_t)b * 768 * 2048 + (size_t)(h * 96) * 2048;

  h16x8 qf[3];
  {
    const u16* Qrow = Q + batch_off + (size_t)(q0 + wave * 16 + l16) * 768 + h * 96 + quad * 8;
    #pragma unroll
    for (int ks = 0; ks < 3; ks++) qf[ks] = *(const h16x8*)(&Qrow[ks * 32]);
  }

  const int kr0 = tid / 12, kc0 = (tid % 12) * 8;
  const int kr1 = (tid + 512) / 12, kc1 = ((tid + 512) % 12) * 8;
  const int vr0 = tid >> 3, vc0 = (tid & 7) * 8;
  const int vr1 = (tid + 512) >> 3, vc1 = ((tid + 512) & 7) * 8;
  const bool extra = tid < 256;

  f32x4 o[6];
  #pragma unroll
  for (int i = 0; i < 6; i++) o[i] = (f32x4){0.f, 0.f, 0.f, 0.f};
  float m_raw = -1e30f, lrow = 0.f;   // lrow: this lane's quad-partial
  const float sc = 0.14724498f;       // log2(e)/sqrt(96)

  u16* Pw = &Ps[wave][0];

  u16x8 kA, kB, vA, vB;
  // ---- prolog: stage tile 0, then load tile 1 into regs ----
  kA = *(const u16x8*)(&Kg[(size_t)kr0 * 768 + kc0]);
  vA = *(const u16x8*)(&Vg[(size_t)vr0 * 2048 + vc0]);
  if (extra) {
    kB = *(const u16x8*)(&Kg[(size_t)kr1 * 768 + kc1]);
    vB = *(const u16x8*)(&Vg[(size_t)vr1 * 2048 + vc1]);
  }
  *(u16x8*)(&Ks[0][kr0 * LQK + kc0]) = kA;
  *(u16x8*)(&Vt[0][vr0 * LVT + vc0]) = vA;
  if (extra) {
    *(u16x8*)(&Ks[0][kr1 * LQK + kc1]) = kB;
    *(u16x8*)(&Vt[0][vr1 * LVT + vc1]) = vB;
  }
  {
    const u16* Kn = Kg + (size_t)64 * 768;
    const u16* Vn = Vg + 64;
    kA = *(const u16x8*)(&Kn[(size_t)kr0 * 768 + kc0]);
    vA = *(const u16x8*)(&Vn[(size_t)vr0 * 2048 + vc0]);
    if (extra) {
      kB = *(const u16x8*)(&Kn[(size_t)kr1 * 768 + kc1]);
      vB = *(const u16x8*)(&Vn[(size_t)vr1 * 2048 + vc1]);
    }
  }
  __syncthreads();

  for (int kt = 0; kt < NT; kt++) {
    const int cur = kt & 1;
    const u16* Kc = &Ks[cur][0];
    const u16* Vc = &Vt[cur][0];

    // QK^T
    f32x4 s[4];
    #pragma unroll
    for (int kf = 0; kf < 4; kf++) s[kf] = (f32x4){0.f, 0.f, 0.f, 0.f};
    __builtin_amdgcn_s_setprio(1);
    #pragma unroll
    for (int ks = 0; ks < 3; ks++) {
      #pragma unroll
      for (int kf = 0; kf < 4; kf++) {
        h16x8 a = *(const h16x8*)(&Kc[(kf * 16 + l16) * LQK + ks * 32 + quad * 8]);
        s[kf] = __builtin_amdgcn_mfma_f32_16x16x32_f16(a, qf[ks], s[kf], 0, 0, 0);
      }
    }
    __builtin_amdgcn_s_setprio(0);

    // online softmax (defer-max T13)
    float mx = s[0][0];
    #pragma unroll
    for (int kf = 0; kf < 4; kf++)
      #pragma unroll
      for (int r = 0; r < 4; r++) mx = fmaxf(mx, s[kf][r]);
    mx = fmaxf(mx, __shfl_xor(mx, 16));
    mx = fmaxf(mx, __shfl_xor(mx, 32));
    if (__any(mx > m_raw + 54.0f)) {
      const float mnew = fmaxf(m_raw, mx);
      const float alpha = exp2f(sc * (m_raw - mnew));   // 0 on first tile
      lrow *= alpha;
      #pragma unroll
      for (int nfo = 0; nfo < 6; nfo++)
        #pragma unroll
        for (int r = 0; r < 4; r++) o[nfo][r] *= alpha;
      m_raw = mnew;
    }
    const float c0 = sc * m_raw;
    float ps = 0.f;
    #pragma unroll
    for (int kf = 0; kf < 4; kf++)
      #pragma unroll
      for (int r = 0; r < 4; r++) {
        float p = exp2f(fmaf(s[kf][r], sc, -c0));
        s[kf][r] = p;
        ps += p;
      }
    lrow += ps;   // quad-partial; cross-quad combine deferred to epilogue

    // P -> LDS (fp16x4, 4 stores)
    #pragma unroll
    for (int kf = 0; kf < 4; kf++) {
      fp16x2 a2 = __builtin_amdgcn_cvt_pkrtz(s[kf][0], s[kf][1]);
      fp16x2 b2 = __builtin_amdgcn_cvt_pkrtz(s[kf][2], s[kf][3]);
      fp16x4 w4; w4[0] = a2[0]; w4[1] = a2[1]; w4[2] = b2[0]; w4[3] = b2[1];
      *(fp16x4*)(&Pw[l16 * LPS + kf * 16 + quad * 4]) = w4;
    }

    // PV
    __builtin_amdgcn_s_setprio(1);
    #pragma unroll
    for (int ks = 0; ks < 2; ks++) {
      h16x8 pfr = *(const h16x8*)(&Pw[l16 * LPS + ks * 32 + quad * 8]);
      #pragma unroll
      for (int nfo = 0; nfo < 6; nfo++) {
        h16x8 vfr = *(const h16x8*)(&Vc[(nfo * 16 + l16) * LVT + ks * 32 + quad * 8]);
        o[nfo] = __builtin_amdgcn_mfma_f32_16x16x32_f16(vfr, pfr, o[nfo], 0, 0, 0);
      }
    }
    __builtin_amdgcn_s_setprio(0);

    // write-late staging of tile kt+1, then issue loads for kt+2
    if (kt + 1 < NT) {
      u16* Kw = &Ks[cur ^ 1][0];
      u16* Vw = &Vt[cur ^ 1][0];
      *(u16x8*)(&Kw[kr0 * LQK + kc0]) = kA;
      *(u16x8*)(&Vw[vr0 * LVT + vc0]) = vA;
      if (extra) {
        *(u16x8*)(&Kw[kr1 * LQK + kc1]) = kB;
        *(u16x8*)(&Vw[vr1 * LVT + vc1]) = vB;
      }
      if (kt + 2 < NT) {
        const u16* Kn = Kg + (size_t)(kt + 2) * 64 * 768;
        const u16* Vn = Vg + (size_t)(kt + 2) * 64;
        kA = *(const u16x8*)(&Kn[(size_t)kr0 * 768 + kc0]);
        vA = *(const u16x8*)(&Vn[(size_t)vr0 * 2048 + vc0]);
        if (extra) {
          kB = *(const u16x8*)(&Kn[(size_t)kr1 * 768 + kc1]);
          vB = *(const u16x8*)(&Vn[(size_t)vr1 * 2048 + vc1]);
        }
      }
      __syncthreads();
    }
  }

  lrow += __shfl_xor(lrow, 16);
  lrow += __shfl_xor(lrow, 32);
  const float inv = 1.0f / lrow;
  u16* Ob = O + batch_off + (size_t)(q0 + wave * 16 + l16) * 768 + h * 96;
  #pragma unroll
  for (int nfo = 0; nfo < 6; nfo++) {
    fp16x2 lo = __builtin_amdgcn_cvt_pkrtz(o[nfo][0] * inv, o[nfo][1] * inv);
    fp16x2 hi = __builtin_amdgcn_cvt_pkrtz(o[nfo][2] * inv, o[nfo][3] * inv);
    *(fp16x2*)(&Ob[nfo * 16 + quad * 4]) = lo;
    *(fp16x2*)(&Ob[nfo * 16 + quad * 4 + 2]) = hi;
  }
}

// ---------------------------------------------------------------------------
extern "C" void kernel_launch(void* const* d_in, const int* in_sizes, int n_in,
                              void* d_out, int out_size, void* d_ws, size_t ws_size,
                              hipStream_t stream) {
  const float* Xq = (const float*)d_in[0];
  const float* Xk = (const float*)d_in[1];
  const float* Xv = (const float*)d_in[2];
  const float* Wq = (const float*)d_in[3];
  const float* bq = (const float*)d_in[4];
  const float* Wk = (const float*)d_in[5];
  const float* bk = (const float*)d_in[6];
  const float* Wv = (const float*)d_in[7];
  const float* bv = (const float*)d_in[8];
  const float* Wo = (const float*)d_in[9];
  const float* bo = (const float*)d_in[10];

  u16* wsu = (u16*)d_ws;
  u16* WT   = wsu;                    // WqT | WkT | WvT, 589824 each
  u16* WoT  = wsu + 3 * 589824;
  u16* Q16  = wsu + 4 * 589824;       // 12.6 MB
  u16* Xk16 = Q16 + 6291456;          // 12.6 MB
  u16* Xv16 = Xk16 + 6291456;         // 12.6 MB
  u16* Xq16 = Xv16 + 6291456;         // 12.6 MB (total 55.05 MB)

  u16* outu = (u16*)d_out;
  u16* VTb = outu;                   // V^T f16 [4][768][2048]
  u16* K16 = outu + 6291456;         // K f16 rowmajor

  u16* A16 = Xk16;                   // attn out overlays Xk16 (dead after
                                     // gemm_qkv) -- d_in never written.

  prep_kernel<<<9648, 256, 0, stream>>>(
      Wq, Wk, Wv, Wo, Xk, Xv, Xq,
      WT, WT + 589824, WT + 2 * 589824, WoT, Xk16, Xv16, Xq16);
  gemm_qkv<<<dim3(64, 6, 3), 256, 0, stream>>>(
      Xq16, Xk16, Xv16, WT, bq, bk, bv, Q16, K16, VTb);
  attn_kernel<<<dim3(16, 32), 512, 0, stream>>>(Q16, K16, VTb, A16);
  gemm_o<<<dim3(64, 6), 256, 0, stream>>>(A16, WoT, bo, (float*)d_out);
}

// Round 7
// 285.974 us; speedup vs baseline: 1.1031x; 1.0027x over previous
//
#include <hip/hip_runtime.h>

// Multi-head attention, B=4 S=2048 D=768 H=8 DH=96. FP32 I/O, f16 MFMA compute.
// R15: gemm_qkv/gemm_o -> 2-phase counted-vmcnt pipeline (T3/T4 minimum):
//      BK=32, dbuf LDS (2x16KB), raw s_barrier + asm vmcnt(4) so next-tile
//      global_load_lds stays in flight across the MFMA phase (the compiler's
//      vmcnt(0)-before-__syncthreads drain was serializing load latency with
//      compute every K-step). attn/prep unchanged from R6 (clean A/B).
// Buffers: ws = [WqT|WkT|WvT|WoT (4.7MB) | Q16 | Xk16 | Xv16 | Xq16] = 55.05MB
//          A16 overlays Xk16 after gemm_qkv (d_in never written).
//          d_out = [VT (12.6MB) | K16 (12.6MB)] f16 until GEMM_O overwrites.

typedef unsigned short u16;
typedef _Float16 h16;
typedef h16 h16x8 __attribute__((ext_vector_type(8)));
typedef __fp16 fp16x2 __attribute__((ext_vector_type(2)));
typedef __fp16 fp16x4 __attribute__((ext_vector_type(4)));
typedef unsigned short u16x8 __attribute__((ext_vector_type(8)));
typedef unsigned short u16x4 __attribute__((ext_vector_type(4)));
typedef float f32x4 __attribute__((ext_vector_type(4)));

__device__ __forceinline__ u16 f2h(float f) {
  union { h16 h; u16 u; } c; c.h = (h16)f; return c.u;
}

__device__ __forceinline__ void gll16(const void* g, void* l) {
  __builtin_amdgcn_global_load_lds(
      (const __attribute__((address_space(1))) void*)g,
      (__attribute__((address_space(3))) void*)l, 16, 0, 0);
}

// ---------------------------------------------------------------------------
// prep: LDS-tiled weight transposes + X f16 conversions (unchanged from R6).
// ---------------------------------------------------------------------------
__global__ __launch_bounds__(256) void prep_kernel(
    const float* __restrict__ Wq, const float* __restrict__ Wk,
    const float* __restrict__ Wv, const float* __restrict__ Wo,
    const float* __restrict__ Xk, const float* __restrict__ Xv,
    const float* __restrict__ Xq,
    u16* __restrict__ WqT, u16* __restrict__ WkT,
    u16* __restrict__ WvT, u16* __restrict__ WoT,
    u16* __restrict__ Xk16, u16* __restrict__ Xv16, u16* __restrict__ Xq16)
{
  const int bid = blockIdx.x;
  const int tid = threadIdx.x;

  if (bid >= 432) {
    const int i = bid - 432;
    const int t = i / 3072;                       // 0: Xk  1: Xv  2: Xq
    const long e = ((long)(i % 3072) * 256 + tid) * 8;
    const float* src = (t == 0) ? Xk : (t == 1) ? Xv : Xq;
    u16* dst = (t == 0) ? Xk16 : (t == 1) ? Xv16 : Xq16;
    f32x4 a = *(const f32x4*)(&src[e]);
    f32x4 b = *(const f32x4*)(&src[e + 4]);
    u16x8 v;
    #pragma unroll
    for (int j = 0; j < 4; j++) { v[j] = f2h(a[j]); v[4 + j] = f2h(b[j]); }
    *(u16x8*)(&dst[e]) = v;
    return;
  }

  if (bid < 288) {
    __shared__ u16 Lt[96][72];
    const int w = bid / 96;
    const int r = bid % 96;
    const int h = r / 12, dt = r % 12;
    const float* W = (w == 0) ? Wq : (w == 1) ? Wk : Wv;
    u16* T = (w == 0) ? WqT : (w == 1) ? WkT : WvT;
    const float* src = W + (size_t)h * 73728 + (size_t)dt * 64 * 96;
    #pragma unroll
    for (int p = 0; p < 6; p++) {
      const int lin = p * 1024 + tid * 4;
      f32x4 v = *(const f32x4*)(&src[lin]);
      const int d = lin / 96, kk = lin % 96;
      #pragma unroll
      for (int j = 0; j < 4; j++) Lt[kk + j][d] = f2h(v[j]);
    }
    __syncthreads();
    #pragma unroll
    for (int c = 0; c < 3; c++) {
      const int ch = c * 256 + tid;
      const int kk = ch >> 3, dc = ch & 7;
      u16x8 o = *(const u16x8*)(&Lt[kk][dc * 8]);
      *(u16x8*)(&T[(size_t)(h * 96 + kk) * 768 + dt * 64 + dc * 8]) = o;
    }
    return;
  }

  {
    __shared__ u16 Lo[64][72];
    const int i = bid - 288;
    const int kt = i / 12, nt = i % 12;
    const float* src = Wo + (size_t)(kt * 64) * 768 + nt * 64;
    #pragma unroll
    for (int p = 0; p < 4; p++) {
      const int lin = p * 1024 + tid * 4;
      const int kr = lin >> 6, nc = lin & 63;
      f32x4 v = *(const f32x4*)(&src[(size_t)kr * 768 + nc]);
      #pragma unroll
      for (int j = 0; j < 4; j++) Lo[nc + j][kr] = f2h(v[j]);
    }
    __syncthreads();
    #pragma unroll
    for (int c = 0; c < 2; c++) {
      const int ch = c * 256 + tid;
      const int nr = ch >> 3, kc = ch & 7;
      u16x8 o = *(const u16x8*)(&Lo[nr][kc * 8]);
      *(u16x8*)(&WoT[(size_t)(nt * 64 + nr) * 768 + kt * 64 + kc * 8]) = o;
    }
  }
}

// ---------------------------------------------------------------------------
// Batched QKV GEMM, BM=128 BN=128 BK=32, 2-phase counted-vmcnt pipeline:
// stage(kt+1) issued BEFORE compute(kt); raw s_barrier; vmcnt(4) keeps the
// next tile's 4 gll16 in flight through the MFMA phase. dbuf LDS 32KB.
// z=2 writes V^T via LDS transpose (coalesced). grid (64, 6, 3), 256 thr.
// ---------------------------------------------------------------------------
#define GK 768

__global__ __launch_bounds__(256) void gemm_qkv(
    const u16* __restrict__ Xq16, const u16* __restrict__ Xk16,
    const u16* __restrict__ Xv16, const u16* __restrict__ WT,
    const float* __restrict__ bq, const float* __restrict__ bk,
    const float* __restrict__ bv,
    u16* __restrict__ Q16, u16* __restrict__ K16, u16* __restrict__ VT)
{
  const int z = blockIdx.z;
  const u16* BT = WT + (size_t)z * 589824;
  const float* bias = (z == 0) ? bq : (z == 1) ? bk : bv;
  const u16* A = (z == 0) ? Xq16 : (z == 1) ? Xk16 : Xv16;

  __shared__ __align__(16) u16 Sb[16384];    // [buf 2][As 4096 | Bs 4096] 32KB

  const int tid = threadIdx.x;
  const int wave = tid >> 6;
  const int lane = tid & 63;
  const int quad = lane >> 4;
  const int l16 = lane & 15;
  const int m0 = blockIdx.x * 128;
  const int n0 = blockIdx.y * 128;

  f32x4 acc[2][8];
  #pragma unroll
  for (int i = 0; i < 2; i++)
    #pragma unroll
    for (int j = 0; j < 8; j++) acc[i][j] = (f32x4){0.f, 0.f, 0.f, 0.f};

  // staging: chunk c -> row=c>>2, col=(c&3)*8 (128x32 tile, u16x8 chunks)
  const int c0 = tid, c1 = tid + 256;
  const u16* gA0 = A + (size_t)(m0 + (c0 >> 2)) * GK + (c0 & 3) * 8;
  const u16* gA1 = A + (size_t)(m0 + (c1 >> 2)) * GK + (c1 & 3) * 8;
  const u16* gB0 = BT + (size_t)(n0 + (c0 >> 2)) * GK + (c0 & 3) * 8;
  const u16* gB1 = BT + (size_t)(n0 + (c1 >> 2)) * GK + (c1 & 3) * 8;
  const int ld0 = (wave * 64) * 8;           // p=0 wave dest (u16)
  const int ld1 = (256 + wave * 64) * 8;     // p=1 wave dest

#define STAGE(buf, kt) do {                                        \
    const int k0_ = (kt) * 32;                                     \
    u16* dst_ = Sb + (buf) * 8192;                                 \
    gll16(gA0 + k0_, dst_ + ld0);                                  \
    gll16(gA1 + k0_, dst_ + ld1);                                  \
    gll16(gB0 + k0_, dst_ + 4096 + ld0);                           \
    gll16(gB1 + k0_, dst_ + 4096 + ld1);                           \
  } while (0)

  STAGE(0, 0);
  int buf = 0;
  for (int kt = 0; kt < 24; kt++) {
    if (kt + 1 < 24) {
      STAGE(buf ^ 1, kt + 1);
      asm volatile("s_waitcnt vmcnt(4)" ::: "memory");   // tile kt landed
    } else {
      asm volatile("s_waitcnt vmcnt(0)" ::: "memory");
    }
    __builtin_amdgcn_s_barrier();

    const u16* As = Sb + buf * 8192;
    const u16* Bs = As + 4096;
    h16x8 af[2], bf[8];
    #pragma unroll
    for (int mf = 0; mf < 2; mf++)
      af[mf] = *(const h16x8*)(&As[(wave * 32 + mf * 16 + l16) * 32 + quad * 8]);
    #pragma unroll
    for (int nf = 0; nf < 8; nf++)
      bf[nf] = *(const h16x8*)(&Bs[(nf * 16 + l16) * 32 + quad * 8]);
    #pragma unroll
    for (int mf = 0; mf < 2; mf++)
      #pragma unroll
      for (int nf = 0; nf < 8; nf++)
        acc[mf][nf] = __builtin_amdgcn_mfma_f32_16x16x32_f16(af[mf], bf[nf], acc[mf][nf], 0, 0, 0);

    __builtin_amdgcn_s_barrier();            // all waves done reading buf
    buf ^= 1;
  }
#undef STAGE

  if (z == 2) {
    // V^T via LDS transpose: Ts[64 n][136] halves, coalesced u16x8 stores.
    const int b = m0 >> 11, s0 = m0 & 2047;
    u16* Ts = Sb;
    #pragma unroll
    for (int half = 0; half < 2; half++) {
      __syncthreads();
      #pragma unroll
      for (int nf2 = 0; nf2 < 4; nf2++) {
        const int nf = half * 4 + nf2;
        const float bv2 = bias[n0 + nf * 16 + l16];
        #pragma unroll
        for (int mf = 0; mf < 2; mf++)
          #pragma unroll
          for (int r = 0; r < 4; r++)
            Ts[(nf2 * 16 + l16) * 136 + wave * 32 + mf * 16 + quad * 4 + r] =
                f2h(acc[mf][nf][r] + bv2);
      }
      __syncthreads();
      #pragma unroll
      for (int p = 0; p < 4; p++) {
        const int c = p * 256 + tid;
        const int row = c >> 4, col8 = (c & 15) * 8;
        u16x8 o8 = *(const u16x8*)(&Ts[row * 136 + col8]);
        *(u16x8*)(&VT[(size_t)b * 768 * 2048 +
                      (size_t)(n0 + half * 64 + row) * 2048 + s0 + col8]) = o8;
      }
    }
    return;
  }

  u16* Yr = (z == 0) ? Q16 : K16;
  #pragma unroll
  for (int nf = 0; nf < 8; nf++) {
    const int n = n0 + nf * 16 + l16;
    const float bv2 = bias[n];
    #pragma unroll
    for (int mf = 0; mf < 2; mf++) {
      const int m = m0 + wave * 32 + mf * 16 + quad * 4;
      #pragma unroll
      for (int r = 0; r < 4; r++)
        Yr[(size_t)(m + r) * GK + n] = f2h(acc[mf][nf][r] + bv2);
    }
  }
}

// ---------------------------------------------------------------------------
// GEMM_O: out[8192][768] fp32 = A16 f16 @ WoT + bo. Same 2-phase pipeline.
// grid (64,6), 256 thr.
// ---------------------------------------------------------------------------
__global__ __launch_bounds__(256) void gemm_o(
    const u16* __restrict__ A, const u16* __restrict__ BT,
    const float* __restrict__ bias, float* __restrict__ Y)
{
  __shared__ __align__(16) u16 Sb[16384];

  const int tid = threadIdx.x;
  const int wave = tid >> 6;
  const int lane = tid & 63;
  const int quad = lane >> 4;
  const int l16 = lane & 15;
  const int m0 = blockIdx.x * 128;
  const int n0 = blockIdx.y * 128;

  f32x4 acc[2][8];
  #pragma unroll
  for (int i = 0; i < 2; i++)
    #pragma unroll
    for (int j = 0; j < 8; j++) acc[i][j] = (f32x4){0.f, 0.f, 0.f, 0.f};

  const int c0 = tid, c1 = tid + 256;
  const u16* gA0 = A + (size_t)(m0 + (c0 >> 2)) * GK + (c0 & 3) * 8;
  const u16* gA1 = A + (size_t)(m0 + (c1 >> 2)) * GK + (c1 & 3) * 8;
  const u16* gB0 = BT + (size_t)(n0 + (c0 >> 2)) * GK + (c0 & 3) * 8;
  const u16* gB1 = BT + (size_t)(n0 + (c1 >> 2)) * GK + (c1 & 3) * 8;
  const int ld0 = (wave * 64) * 8;
  const int ld1 = (256 + wave * 64) * 8;

#define STAGE(buf, kt) do {                                        \
    const int k0_ = (kt) * 32;                                     \
    u16* dst_ = Sb + (buf) * 8192;                                 \
    gll16(gA0 + k0_, dst_ + ld0);                                  \
    gll16(gA1 + k0_, dst_ + ld1);                                  \
    gll16(gB0 + k0_, dst_ + 4096 + ld0);                           \
    gll16(gB1 + k0_, dst_ + 4096 + ld1);                           \
  } while (0)

  STAGE(0, 0);
  int buf = 0;
  for (int kt = 0; kt < 24; kt++) {
    if (kt + 1 < 24) {
      STAGE(buf ^ 1, kt + 1);
      asm volatile("s_waitcnt vmcnt(4)" ::: "memory");
    } else {
      asm volatile("s_waitcnt vmcnt(0)" ::: "memory");
    }
    __builtin_amdgcn_s_barrier();

    const u16* As = Sb + buf * 8192;
    const u16* Bs = As + 4096;
    h16x8 af[2], bf[8];
    #pragma unroll
    for (int mf = 0; mf < 2; mf++)
      af[mf] = *(const h16x8*)(&As[(wave * 32 + mf * 16 + l16) * 32 + quad * 8]);
    #pragma unroll
    for (int nf = 0; nf < 8; nf++)
      bf[nf] = *(const h16x8*)(&Bs[(nf * 16 + l16) * 32 + quad * 8]);
    #pragma unroll
    for (int mf = 0; mf < 2; mf++)
      #pragma unroll
      for (int nf = 0; nf < 8; nf++)
        acc[mf][nf] = __builtin_amdgcn_mfma_f32_16x16x32_f16(af[mf], bf[nf], acc[mf][nf], 0, 0, 0);

    __builtin_amdgcn_s_barrier();
    buf ^= 1;
  }
#undef STAGE

  #pragma unroll
  for (int nf = 0; nf < 8; nf++) {
    const int n = n0 + nf * 16 + l16;
    const float bv = bias[n];
    #pragma unroll
    for (int mf = 0; mf < 2; mf++) {
      const int m = m0 + wave * 32 + mf * 16 + quad * 4;
      #pragma unroll
      for (int r = 0; r < 4; r++)
        Y[(size_t)(m + r) * GK + n] = acc[mf][nf][r] + bv;
    }
  }
}

// ---------------------------------------------------------------------------
// Flash attention (unchanged R6: dbuf K/V, one barrier/iter, write-late).
// 512 thr / 8 waves x 16 q-rows, grid (16,32). LDS 72.7KB -> 2 blocks/CU.
// defer-max (T13); setprio (T5).
// ---------------------------------------------------------------------------
#define SEQ 2048
#define NT 32
#define LQK 104
#define LVT 72
#define LPS 72

__global__ __launch_bounds__(512, 4) void attn_kernel(
    const u16* __restrict__ Q, const u16* __restrict__ K,
    const u16* __restrict__ VT, u16* __restrict__ O)
{
  __shared__ __align__(16) u16 Ks[2][64 * LQK];
  __shared__ __align__(16) u16 Vt[2][96 * LVT];
  __shared__ __align__(16) u16 Ps[8][16 * LPS];

  const int tid = threadIdx.x;
  const int wave = tid >> 6;
  const int lane = tid & 63;
  const int quad = lane >> 4;
  const int l16 = lane & 15;

  const int bh = blockIdx.y;
  const int b = bh >> 3, h = bh & 7;
  const int q0 = blockIdx.x * 128;

  const size_t batch_off = (size_t)b * SEQ * 768;
  const u16* Kg = K + batch_off + h * 96;
  const u16* Vg = VT + (size_t)b * 768 * 2048 + (size_t)(h * 96) * 2048;

  h16x8 qf[3];
  {
    const u16* Qrow = Q + batch_off + (size_t)(q0 + wave * 16 + l16) * 768 + h * 96 + quad * 8;
    #pragma unroll
    for (int ks = 0; ks < 3; ks++) qf[ks] = *(const h16x8*)(&Qrow[ks * 32]);
  }

  const int kr0 = tid / 12, kc0 = (tid % 12) * 8;
  const int kr1 = (tid + 512) / 12, kc1 = ((tid + 512) % 12) * 8;
  const int vr0 = tid >> 3, vc0 = (tid & 7) * 8;
  const int vr1 = (tid + 512) >> 3, vc1 = ((tid + 512) & 7) * 8;
  const bool extra = tid < 256;

  f32x4 o[6];
  #pragma unroll
  for (int i = 0; i < 6; i++) o[i] = (f32x4){0.f, 0.f, 0.f, 0.f};
  float m_raw = -1e30f, lrow = 0.f;   // lrow: this lane's quad-partial
  const float sc = 0.14724498f;       // log2(e)/sqrt(96)

  u16* Pw = &Ps[wave][0];

  u16x8 kA, kB, vA, vB;
  kA = *(const u16x8*)(&Kg[(size_t)kr0 * 768 + kc0]);
  vA = *(const u16x8*)(&Vg[(size_t)vr0 * 2048 + vc0]);
  if (extra) {
    kB = *(const u16x8*)(&Kg[(size_t)kr1 * 768 + kc1]);
    vB = *(const u16x8*)(&Vg[(size_t)vr1 * 2048 + vc1]);
  }
  *(u16x8*)(&Ks[0][kr0 * LQK + kc0]) = kA;
  *(u16x8*)(&Vt[0][vr0 * LVT + vc0]) = vA;
  if (extra) {
    *(u16x8*)(&Ks[0][kr1 * LQK + kc1]) = kB;
    *(u16x8*)(&Vt[0][vr1 * LVT + vc1]) = vB;
  }
  {
    const u16* Kn = Kg + (size_t)64 * 768;
    const u16* Vn = Vg + 64;
    kA = *(const u16x8*)(&Kn[(size_t)kr0 * 768 + kc0]);
    vA = *(const u16x8*)(&Vn[(size_t)vr0 * 2048 + vc0]);
    if (extra) {
      kB = *(const u16x8*)(&Kn[(size_t)kr1 * 768 + kc1]);
      vB = *(const u16x8*)(&Vn[(size_t)vr1 * 2048 + vc1]);
    }
  }
  __syncthreads();

  for (int kt = 0; kt < NT; kt++) {
    const int cur = kt & 1;
    const u16* Kc = &Ks[cur][0];
    const u16* Vc = &Vt[cur][0];

    f32x4 s[4];
    #pragma unroll
    for (int kf = 0; kf < 4; kf++) s[kf] = (f32x4){0.f, 0.f, 0.f, 0.f};
    __builtin_amdgcn_s_setprio(1);
    #pragma unroll
    for (int ks = 0; ks < 3; ks++) {
      #pragma unroll
      for (int kf = 0; kf < 4; kf++) {
        h16x8 a = *(const h16x8*)(&Kc[(kf * 16 + l16) * LQK + ks * 32 + quad * 8]);
        s[kf] = __builtin_amdgcn_mfma_f32_16x16x32_f16(a, qf[ks], s[kf], 0, 0, 0);
      }
    }
    __builtin_amdgcn_s_setprio(0);

    float mx = s[0][0];
    #pragma unroll
    for (int kf = 0; kf < 4; kf++)
      #pragma unroll
      for (int r = 0; r < 4; r++) mx = fmaxf(mx, s[kf][r]);
    mx = fmaxf(mx, __shfl_xor(mx, 16));
    mx = fmaxf(mx, __shfl_xor(mx, 32));
    if (__any(mx > m_raw + 54.0f)) {
      const float mnew = fmaxf(m_raw, mx);
      const float alpha = exp2f(sc * (m_raw - mnew));   // 0 on first tile
      lrow *= alpha;
      #pragma unroll
      for (int nfo = 0; nfo < 6; nfo++)
        #pragma unroll
        for (int r = 0; r < 4; r++) o[nfo][r] *= alpha;
      m_raw = mnew;
    }
    const float c0f = sc * m_raw;
    float ps = 0.f;
    #pragma unroll
    for (int kf = 0; kf < 4; kf++)
      #pragma unroll
      for (int r = 0; r < 4; r++) {
        float p = exp2f(fmaf(s[kf][r], sc, -c0f));
        s[kf][r] = p;
        ps += p;
      }
    lrow += ps;   // quad-partial; cross-quad combine deferred to epilogue

    #pragma unroll
    for (int kf = 0; kf < 4; kf++) {
      fp16x2 a2 = __builtin_amdgcn_cvt_pkrtz(s[kf][0], s[kf][1]);
      fp16x2 b2 = __builtin_amdgcn_cvt_pkrtz(s[kf][2], s[kf][3]);
      fp16x4 w4; w4[0] = a2[0]; w4[1] = a2[1]; w4[2] = b2[0]; w4[3] = b2[1];
      *(fp16x4*)(&Pw[l16 * LPS + kf * 16 + quad * 4]) = w4;
    }

    __builtin_amdgcn_s_setprio(1);
    #pragma unroll
    for (int ks = 0; ks < 2; ks++) {
      h16x8 pfr = *(const h16x8*)(&Pw[l16 * LPS + ks * 32 + quad * 8]);
      #pragma unroll
      for (int nfo = 0; nfo < 6; nfo++) {
        h16x8 vfr = *(const h16x8*)(&Vc[(nfo * 16 + l16) * LVT + ks * 32 + quad * 8]);
        o[nfo] = __builtin_amdgcn_mfma_f32_16x16x32_f16(vfr, pfr, o[nfo], 0, 0, 0);
      }
    }
    __builtin_amdgcn_s_setprio(0);

    if (kt + 1 < NT) {
      u16* Kw = &Ks[cur ^ 1][0];
      u16* Vw = &Vt[cur ^ 1][0];
      *(u16x8*)(&Kw[kr0 * LQK + kc0]) = kA;
      *(u16x8*)(&Vw[vr0 * LVT + vc0]) = vA;
      if (extra) {
        *(u16x8*)(&Kw[kr1 * LQK + kc1]) = kB;
        *(u16x8*)(&Vw[vr1 * LVT + vc1]) = vB;
      }
      if (kt + 2 < NT) {
        const u16* Kn = Kg + (size_t)(kt + 2) * 64 * 768;
        const u16* Vn = Vg + (size_t)(kt + 2) * 64;
        kA = *(const u16x8*)(&Kn[(size_t)kr0 * 768 + kc0]);
        vA = *(const u16x8*)(&Vn[(size_t)vr0 * 2048 + vc0]);
        if (extra) {
          kB = *(const u16x8*)(&Kn[(size_t)kr1 * 768 + kc1]);
          vB = *(const u16x8*)(&Vn[(size_t)vr1 * 2048 + vc1]);
        }
      }
      __syncthreads();
    }
  }

  lrow += __shfl_xor(lrow, 16);
  lrow += __shfl_xor(lrow, 32);
  const float inv = 1.0f / lrow;
  u16* Ob = O + batch_off + (size_t)(q0 + wave * 16 + l16) * 768 + h * 96;
  #pragma unroll
  for (int nfo = 0; nfo < 6; nfo++) {
    fp16x2 lo = __builtin_amdgcn_cvt_pkrtz(o[nfo][0] * inv, o[nfo][1] * inv);
    fp16x2 hi = __builtin_amdgcn_cvt_pkrtz(o[nfo][2] * inv, o[nfo][3] * inv);
    *(fp16x2*)(&Ob[nfo * 16 + quad * 4]) = lo;
    *(fp16x2*)(&Ob[nfo * 16 + quad * 4 + 2]) = hi;
  }
}

// ---------------------------------------------------------------------------
extern "C" void kernel_launch(void* const* d_in, const int* in_sizes, int n_in,
                              void* d_out, int out_size, void* d_ws, size_t ws_size,
                              hipStream_t stream) {
  const float* Xq = (const float*)d_in[0];
  const float* Xk = (const float*)d_in[1];
  const float* Xv = (const float*)d_in[2];
  const float* Wq = (const float*)d_in[3];
  const float* bq = (const float*)d_in[4];
  const float* Wk = (const float*)d_in[5];
  const float* bk = (const float*)d_in[6];
  const float* Wv = (const float*)d_in[7];
  const float* bv = (const float*)d_in[8];
  const float* Wo = (const float*)d_in[9];
  const float* bo = (const float*)d_in[10];

  u16* wsu = (u16*)d_ws;
  u16* WT   = wsu;                    // WqT | WkT | WvT, 589824 each
  u16* WoT  = wsu + 3 * 589824;
  u16* Q16  = wsu + 4 * 589824;       // 12.6 MB
  u16* Xk16 = Q16 + 6291456;          // 12.6 MB
  u16* Xv16 = Xk16 + 6291456;         // 12.6 MB
  u16* Xq16 = Xv16 + 6291456;         // 12.6 MB (total 55.05 MB)

  u16* outu = (u16*)d_out;
  u16* VTb = outu;                   // V^T f16 [4][768][2048]
  u16* K16 = outu + 6291456;         // K f16 rowmajor

  u16* A16 = Xk16;                   // attn out overlays Xk16 (dead after
                                     // gemm_qkv) -- d_in never written.

  prep_kernel<<<9648, 256, 0, stream>>>(
      Wq, Wk, Wv, Wo, Xk, Xv, Xq,
      WT, WT + 589824, WT + 2 * 589824, WoT, Xk16, Xv16, Xq16);
  gemm_qkv<<<dim3(64, 6, 3), 256, 0, stream>>>(
      Xq16, Xk16, Xv16, WT, bq, bk, bv, Q16, K16, VTb);
  attn_kernel<<<dim3(16, 32), 512, 0, stream>>>(Q16, K16, VTb, A16);
  gemm_o<<<dim3(64, 6), 256, 0, stream>>>(A16, WoT, bo, (float*)d_out);
}